// Round 3
// baseline (240.003 us; speedup 1.0000x reference)
//
#include <hip/hip_runtime.h>

// Problem constants
#define INC    256
#define HIN    56
#define WIN    56
#define HOUT   19
#define WOUT   58
#define HW     3136          // HIN*WIN

typedef short frag8 __attribute__((ext_vector_type(8)));   // 8 bf16 bits (4 VGPRs)
typedef float f32x4 __attribute__((ext_vector_type(4)));   // MFMA accumulator
typedef float f4    __attribute__((ext_vector_type(4)));

static __device__ __forceinline__ unsigned short f2bf(float f) {
    unsigned u = __float_as_uint(f);
    u += 0x7fffu + ((u >> 16) & 1u);      // round-to-nearest-even
    return (unsigned short)(u >> 16);
}

// f32 pair -> packed 2x bf16 (RNE), lo16 = a, hi16 = b
static __device__ __forceinline__ unsigned cvtpk(float a, float b) {
    unsigned r;
    asm("v_cvt_pk_bf16_f32 %0, %1, %2" : "=v"(r) : "v"(a), "v"(b));
    return r;
}

#define VMCNT(n) asm volatile("s_waitcnt vmcnt(" #n ")" ::: "memory")
#define FENCE()  asm volatile("" ::: "memory")

// ---------------------------------------------------------------------------
// prep_weff: unchanged. Folds sparse einsum into dense conv weights in MFMA
// A-fragment-linear order: Asw[o_tile 16][ks 24][lane 64][j 8] bf16.
// ---------------------------------------------------------------------------
__global__ __launch_bounds__(256) void prep_weff(
    const float* __restrict__ lego,    // [64][64][3]
    const float* __restrict__ coefs,   // [4][256][64]
    const float* __restrict__ comb,    // [4][256][64]
    unsigned short* __restrict__ Asw)
{
    __shared__ int   idxS[4];
    __shared__ float cofS[4];
    const int t  = threadIdx.x;
    const int kx = blockIdx.x;         // 0..2
    const int o  = blockIdx.y;         // 0..255
    const int wv = t >> 6, l = t & 63;

    float v  = comb[(wv * 256 + o) * 64 + l];
    int   bi = l;
    #pragma unroll
    for (int off = 32; off >= 1; off >>= 1) {
        float ov = __shfl_xor(v, off, 64);
        int   oi = __shfl_xor(bi, off, 64);
        if (ov > v || (ov == v && oi < bi)) { v = ov; bi = oi; }
    }
    if (l == 0) {
        idxS[wv] = bi;
        cofS[wv] = coefs[(wv * 256 + o) * 64 + bi];
    }
    __syncthreads();

    const int k  = kx * 256 + t;       // 0..767
    const int kh = k >> 8, c = k & 255;
    const int i  = c >> 6, cl = c & 63;
    float w = cofS[i] * lego[idxS[i] * 192 + cl * 3 + kh];

    const int o_tile = o >> 4, m = o & 15;
    const int ks = k >> 5, kc = (k >> 3) & 3, j = k & 7;
    Asw[((((size_t)o_tile * 24 + ks) * 64) + kc * 16 + m) * 8 + j] = f2bf(w);
}

// ---------------------------------------------------------------------------
// R7 conv. Same skeleton as R6 (one block per (b,h), 4 waves, 256o x 64w tile,
// gll staging of f32, 3x16KB buffers, counted vmcnt + raw s_barrier), with the
// two R6 post-mortem fixes:
//  (1) A-FRAGMENT FIFO BUG: R6 loaded chunk-q A frags AFTER STAGE(q+2); A(q)
//      was the newest vmem op, so the compiler's wait before the MFMAs was a
//      de-facto vmcnt(0) -> drained stage(q+1)/(q+2) every chunk (pipeline
//      depth 0, hence R6 == R4 time). Now A is double-buffered: A(q+1) is
//      prefetched at the TOP of iter q, pinned above STAGE(q+2) by
//      sched_barrier(0). Retire set at VMCNT(16) = {...,stage(q),A(q)};
//      in-flight set = stage(q+1)+A(q+1)+stage(q+2) = 16. Tail: q=10 -> 12,
//      q=11 -> 0. (h==0: stage(0) is ds_write, 0 vmem ops -- counts checked.)
//  (2) BANK CONFLICTS (3.74M = 2cy per ds_read): wave64 b32 LDS reads run as
//      two 32-lane phases; the old 8*kc rotation made each phase hit 8 banks
//      twice. Rotation is now 16*kc: each 32-lane phase covers all 32 banks
//      exactly once. Inverse on the pre-swizzled global source is 4*kc col
//      groups. Predicted conflicts ~0.
// ---------------------------------------------------------------------------
__global__ __launch_bounds__(256, 3) void conv_mfma(
    const float* __restrict__ x,             // [32][256][56][56]
    const unsigned short* __restrict__ Asw,  // [16][24][64][8]
    float* __restrict__ out)                 // [32][256][19][58]
{
    __shared__ float Xs[3][4096];            // 3 x 16KB staging buffers

    const int t  = threadIdx.x;
    const int h  = blockIdx.x;               // 0..18
    const int b  = blockIdx.y;               // 0..31
    const int l  = t & 63;
    const int lo = l & 15;
    const int hi = l >> 4;                   // = kc for A/B fragment lanes
    const int wv = t >> 6;
    const int kc = hi;

    // ---- B-read per-lane constants: addr = buf + kc*2048 + slotb[wt]
    //      + (ksl*8192 + j*256) [immediate]
    int slotb[4];
    #pragma unroll
    for (int wt = 0; wt < 4; ++wt) {
        int c    = wt * 16 + lo;
        int slot = (c & 32) | ((c + 16 * kc) & 31);   // 16*kc: per-phase-free
        slotb[wt] = slot * 4;
    }
    const int bko = kc * 2048;

    // ---- staging per-lane constants (lane-linear LDS dest, swizzled source)
    const int gs = l & 15, chof = l >> 4;
    unsigned goff[4];                        // global float offset per instr
    int      ldsu[4];                        // wave-uniform LDS byte base
    #pragma unroll
    for (int i = 0; i < 4; ++i) {
        int I    = wv * 4 + i;               // instr 0..15 within chunk
        int chl  = I * 4 + chof;             // channel-local 0..63
        int kcs  = (chl >> 3) & 3;
        int half = gs >> 3, gsw = gs & 7;
        int g    = (gsw - 4 * kcs) & 7;      // inverse of 16*kc slot rotation
        int col  = half * 32 + g * 4;
        if (col >= WIN) col = 0;             // OOB cols 56..63: safe garbage,
                                             // feeds only discarded outputs
        goff[i] = (unsigned)chl * HW + col;
        ldsu[i] = I * 1024;                  // HW adds lane*16
    }

    const float* xb = x + (size_t)b * (INC * HW);
    const frag8* Af = (const frag8*)Asw + (size_t)(wv * 4) * 24 * 64 + l;
    char* XsB = (char*)&Xs[0][0];

    f32x4 acc[4][4];
    #pragma unroll
    for (int ot = 0; ot < 4; ++ot)
        #pragma unroll
        for (int wt = 0; wt < 4; ++wt)
            acc[ot][wt] = (f32x4){0.f, 0.f, 0.f, 0.f};

    // stage chunk q into buf q%3: 4 gll instrs/wave (or ds_write zeros for
    // the padded row h==0,kh==0; block-uniform branch, no barrier inside)
    auto STAGE = [&](int q) {
        const int kh = q >> 2, cq = q & 3;
        const int row = 3 * h - 1 + kh;
        const int bufo = (q % 3) * 16384;
        if (row < 0) {                       // only h==0, kh==0
            f4 z = (f4){0.f, 0.f, 0.f, 0.f};
            #pragma unroll
            for (int i = 0; i < 4; ++i)
                *(f4*)(XsB + bufo + ldsu[i] + l * 16) = z;
            asm volatile("s_waitcnt lgkmcnt(0)" ::: "memory");
        } else {
            const float* rp = xb + (size_t)cq * 64 * HW + row * WIN;
            #pragma unroll
            for (int i = 0; i < 4; ++i) {
                __builtin_amdgcn_global_load_lds(
                    (const __attribute__((address_space(1))) void*)(rp + goff[i]),
                    (__attribute__((address_space(3))) void*)(XsB + bufo + ldsu[i]),
                    16, 0, 0);
            }
        }
    };

    // A-fragment double buffer: A2[p][ot][ksl], p = chunk parity
    frag8 A2[2][4][2];
    #pragma unroll
    for (int ot = 0; ot < 4; ++ot)
        #pragma unroll
        for (int ksl = 0; ksl < 2; ++ksl)
            A2[0][ot][ksl] = Af[(ot * 24 + 0 * 2 + ksl) * 64];
    __builtin_amdgcn_sched_barrier(0);       // A(0) issues before stage(0)
    STAGE(0);
    STAGE(1);

    #pragma unroll
    for (int q = 0; q < 12; ++q) {
        // ---- A(q+1) prefetch FIRST (must be older than stage(q+2) in FIFO)
        if (q + 1 < 12) {
            #pragma unroll
            for (int ot = 0; ot < 4; ++ot)
                #pragma unroll
                for (int ksl = 0; ksl < 2; ++ksl)
                    A2[(q + 1) & 1][ot][ksl] = Af[(ot * 24 + (q + 1) * 2 + ksl) * 64];
        }
        __builtin_amdgcn_sched_barrier(0);   // pin A(q+1) above STAGE(q+2)
        if (q + 2 < 12) STAGE(q + 2);

        // counted wait: retire through stage(q)+A(q); keep newest 16 =
        // stage(q+1)4 + A(q+1)8 + stage(q+2)4 in flight
        if (q < 10)       { VMCNT(16); }
        else if (q == 10) { VMCNT(12); }
        else              { VMCNT(0);  }
        __builtin_amdgcn_s_barrier();        // buf q%3 ready for all waves
        FENCE();

        const char* bb = XsB + (q % 3) * 16384 + bko;
        #pragma unroll
        for (int ksl = 0; ksl < 2; ++ksl) {
            #pragma unroll
            for (int wt = 0; wt < 4; ++wt) {
                const char* p0 = bb + ksl * 8192 + slotb[wt];
                float f0 = *(const float*)(p0 + 0 * 256);
                float f1 = *(const float*)(p0 + 1 * 256);
                float f2 = *(const float*)(p0 + 2 * 256);
                float f3 = *(const float*)(p0 + 3 * 256);
                float f4_ = *(const float*)(p0 + 4 * 256);
                float f5 = *(const float*)(p0 + 5 * 256);
                float f6 = *(const float*)(p0 + 6 * 256);
                float f7 = *(const float*)(p0 + 7 * 256);
                union { frag8 fr; unsigned u[4]; } B;
                B.u[0] = cvtpk(f0, f1);
                B.u[1] = cvtpk(f2, f3);
                B.u[2] = cvtpk(f4_, f5);
                B.u[3] = cvtpk(f6, f7);
                #pragma unroll
                for (int ot = 0; ot < 4; ++ot)
                    acc[ot][wt] = __builtin_amdgcn_mfma_f32_16x16x32_bf16(
                        A2[q & 1][ot][ksl], B.fr, acc[ot][wt], 0, 0, 0);
            }
        }
        FENCE();
        __builtin_amdgcn_s_barrier();        // all reads of buf q%3 done
    }

    // ---- store: out col = n+1 for n=0..55; cols 0 and 57 are exact zeros
    #pragma unroll
    for (int ot = 0; ot < 4; ++ot) {
        #pragma unroll
        for (int r = 0; r < 4; ++r) {
            int o = wv * 64 + ot * 16 + hi * 4 + r;
            float* orow = out + ((size_t)(b * 256 + o) * HOUT + h) * WOUT;
            #pragma unroll
            for (int wt = 0; wt < 4; ++wt) {
                int n = wt * 16 + lo;
                if (n < 56) orow[n + 1] = acc[ot][wt][r];
            }
            if (lo == 0) orow[0]  = 0.f;
            if (lo == 1) orow[57] = 0.f;
        }
    }
}

extern "C" void kernel_launch(void* const* d_in, const int* in_sizes, int n_in,
                              void* d_out, int out_size, void* d_ws, size_t ws_size,
                              hipStream_t stream) {
    const float* x     = (const float*)d_in[0];   // (32,256,56,56)
    const float* lego  = (const float*)d_in[1];   // (64,64,3,1)
    const float* coefs = (const float*)d_in[2];   // (4,256,64,1,1)
    const float* comb  = (const float*)d_in[3];   // (4,256,64,1,1)
    float* out = (float*)d_out;                   // (32,256,19,58)

    unsigned short* Asw = (unsigned short*)d_ws;  // 196,608 bf16 = 384 KB

    prep_weff<<<dim3(3, 256), 256, 0, stream>>>(lego, coefs, comb, Asw);
    conv_mfma<<<dim3(HOUT, 32), 256, 0, stream>>>(x, Asw, out);
}

// Round 4
// 195.382 us; speedup vs baseline: 1.2284x; 1.2284x over previous
//
#include <hip/hip_runtime.h>

// Problem constants
#define INC    256
#define HIN    56
#define WIN    56
#define HOUT   19
#define WOUT   58
#define HW     3136          // HIN*WIN

typedef short frag8 __attribute__((ext_vector_type(8)));   // 8 bf16 bits (4 VGPRs)
typedef float f32x4 __attribute__((ext_vector_type(4)));   // MFMA accumulator
typedef float f4    __attribute__((ext_vector_type(4)));

static __device__ __forceinline__ unsigned short f2bf(float f) {
    unsigned u = __float_as_uint(f);
    u += 0x7fffu + ((u >> 16) & 1u);      // round-to-nearest-even
    return (unsigned short)(u >> 16);
}

// f32 pair -> packed 2x bf16 (RNE), lo16 = a, hi16 = b
static __device__ __forceinline__ unsigned cvtpk(float a, float b) {
    unsigned r;
    asm("v_cvt_pk_bf16_f32 %0, %1, %2" : "=v"(r) : "v"(a), "v"(b));
    return r;
}

#define VMCNT(n) asm volatile("s_waitcnt vmcnt(" #n ")" ::: "memory")
#define FENCE()  asm volatile("" ::: "memory")

// ---------------------------------------------------------------------------
// prep_weff: folds sparse einsum into dense conv weights.
// R8 layout change: CHUNK-MAJOR so conv's per-iteration A-loads are one base +
// small immediate offsets:
//   Asw[ks2 12][o_tile 16][ksl 2][lane 64][j 8] bf16, ks2 = ks>>1, ksl = ks&1
// ---------------------------------------------------------------------------
__global__ __launch_bounds__(256) void prep_weff(
    const float* __restrict__ lego,    // [64][64][3]
    const float* __restrict__ coefs,   // [4][256][64]
    const float* __restrict__ comb,    // [4][256][64]
    unsigned short* __restrict__ Asw)
{
    __shared__ int   idxS[4];
    __shared__ float cofS[4];
    const int t  = threadIdx.x;
    const int kx = blockIdx.x;         // 0..2
    const int o  = blockIdx.y;         // 0..255
    const int wv = t >> 6, l = t & 63;

    float v  = comb[(wv * 256 + o) * 64 + l];
    int   bi = l;
    #pragma unroll
    for (int off = 32; off >= 1; off >>= 1) {
        float ov = __shfl_xor(v, off, 64);
        int   oi = __shfl_xor(bi, off, 64);
        if (ov > v || (ov == v && oi < bi)) { v = ov; bi = oi; }
    }
    if (l == 0) {
        idxS[wv] = bi;
        cofS[wv] = coefs[(wv * 256 + o) * 64 + bi];
    }
    __syncthreads();

    const int k  = kx * 256 + t;       // 0..767
    const int kh = k >> 8, c = k & 255;
    const int i  = c >> 6, cl = c & 63;
    float w = cofS[i] * lego[idxS[i] * 192 + cl * 3 + kh];

    const int o_tile = o >> 4, m = o & 15;
    const int ks = k >> 5, kc = (k >> 3) & 3, j = k & 7;
    const int ks2 = ks >> 1, ksl = ks & 1;
    Asw[((((size_t)ks2 * 16 + o_tile) * 2 + ksl) * 64 + kc * 16 + m) * 8 + j] = f2bf(w);
}

// ---------------------------------------------------------------------------
// R8 conv. R7 skeleton (one block/(b,h), 4 waves, 256o x 64w, gll f32 staging,
// 3 x 16KB buffers, counted vmcnt + raw s_barrier, 16*kc bank rotation) with
// the R7 post-mortem fixes:
//  (1) SPILL (WRITE_SIZE 39->105MB): A2 double-buffer (64 VGPR) pushed the
//      unified VGPR+AGPR count to ~174 > the (256,3) cap ~170. Removed. FIFO
//      correctness is instead obtained by ISSUE ORDER: A(q+1) is loaded into
//      the (dead) A regs AFTER compute(q), so the stream is
//        ..., A(q), st(q+1), [iter q: compute; A(q+1); st(q+2)]
//      At iter q's head, VMCNT(4) retires {st(q), A(q)} and leaves st(q+1)
//      in flight; st(q+2) gets ~2 iterations of lead. Tail: q==11 -> VMCNT(0).
//      h==0: STAGE(0) is ds_write (0 vmem ops), counts still work.
//  (2) ONE barrier per chunk (was 2): barrier at iter q's head already proves
//      all waves finished compute(q-1); STAGE(q+2) (issued post-compute in
//      iter q) overwrites buf (q-1)%3 whose readers all passed this barrier.
//  (3) A-loads: chunk-major Asw layout -> 8 loads = 1 base + imm offsets.
// Registers: acc 64 + A 32 + ~40 misc ~= 137 << 170 cap. LDS 48KB.
// 3 blocks/CU, 12 waves/CU.
// ---------------------------------------------------------------------------
__global__ __launch_bounds__(256, 3) void conv_mfma(
    const float* __restrict__ x,             // [32][256][56][56]
    const unsigned short* __restrict__ Asw,  // [12][16][2][64][8]
    float* __restrict__ out)                 // [32][256][19][58]
{
    __shared__ float Xs[3][4096];            // 3 x 16KB staging buffers

    const int t  = threadIdx.x;
    const int h  = blockIdx.x;               // 0..18
    const int b  = blockIdx.y;               // 0..31
    const int l  = t & 63;
    const int lo = l & 15;
    const int hi = l >> 4;                   // = kc for A/B fragment lanes
    const int wv = t >> 6;
    const int kc = hi;

    // ---- B-read per-lane constants: addr = buf + kc*2048 + slotb[wt]
    int slotb[4];
    #pragma unroll
    for (int wt = 0; wt < 4; ++wt) {
        int c    = wt * 16 + lo;
        int slot = (c & 32) | ((c + 16 * kc) & 31);   // per-32-lane-phase free
        slotb[wt] = slot * 4;
    }
    const int bko = kc * 2048;

    // ---- staging per-lane constants (lane-linear LDS dest, swizzled source)
    const int gs = l & 15, chof = l >> 4;
    unsigned goff[4];                        // global float offset per instr
    int      ldsu[4];                        // wave-uniform LDS byte base
    #pragma unroll
    for (int i = 0; i < 4; ++i) {
        int I    = wv * 4 + i;               // instr 0..15 within chunk
        int chl  = I * 4 + chof;             // channel-local 0..63
        int kcs  = (chl >> 3) & 3;
        int half = gs >> 3, gsw = gs & 7;
        int g    = (gsw - 4 * kcs) & 7;      // inverse of 16*kc slot rotation
        int col  = half * 32 + g * 4;
        if (col >= WIN) col = 0;             // OOB cols 56..63: safe garbage,
                                             // feeds only discarded outputs
        goff[i] = (unsigned)chl * HW + col;
        ldsu[i] = I * 1024;                  // HW adds lane*16
    }

    const float* xb = x + (size_t)b * (INC * HW);
    const frag8* Afw = (const frag8*)Asw + l;   // + q*2048 + wv*512 + ot*128 + ksl*64
    char* XsB = (char*)&Xs[0][0];

    f32x4 acc[4][4];
    #pragma unroll
    for (int ot = 0; ot < 4; ++ot)
        #pragma unroll
        for (int wt = 0; wt < 4; ++wt)
            acc[ot][wt] = (f32x4){0.f, 0.f, 0.f, 0.f};

    // stage chunk q into buf q%3: 4 gll instrs/wave (or ds_write zeros for
    // the padded row h==0,kh==0; block-uniform branch)
    auto STAGE = [&](int q) {
        const int kh = q >> 2, cq = q & 3;
        const int row = 3 * h - 1 + kh;
        const int bufo = (q % 3) * 16384;
        if (row < 0) {                       // only h==0, kh==0 (prologue)
            f4 z = (f4){0.f, 0.f, 0.f, 0.f};
            #pragma unroll
            for (int i = 0; i < 4; ++i)
                *(f4*)(XsB + bufo + ldsu[i] + l * 16) = z;
            asm volatile("s_waitcnt lgkmcnt(0)" ::: "memory");
        } else {
            const float* rp = xb + (size_t)cq * 64 * HW + row * WIN;
            #pragma unroll
            for (int i = 0; i < 4; ++i) {
                __builtin_amdgcn_global_load_lds(
                    (const __attribute__((address_space(1))) void*)(rp + goff[i]),
                    (__attribute__((address_space(3))) void*)(XsB + bufo + ldsu[i]),
                    16, 0, 0);
            }
        }
    };

    // A fragments, single-buffered: A(q+1) loads reuse these regs post-compute
    frag8 A[4][2];
    #pragma unroll
    for (int ot = 0; ot < 4; ++ot)
        #pragma unroll
        for (int ksl = 0; ksl < 2; ++ksl)
            A[ot][ksl] = Afw[wv * 512 + ot * 128 + ksl * 64];   // A(0)
    __builtin_amdgcn_sched_barrier(0);       // A(0) older than stage(0) in FIFO
    STAGE(0);
    STAGE(1);

    #pragma unroll
    for (int q = 0; q < 12; ++q) {
        // retire {st(q), A(q)}; keep st(q+1) (and anything newer) in flight
        if (q == 11) { VMCNT(0); } else { VMCNT(4); }
        __builtin_amdgcn_s_barrier();        // buf q%3 ready for all waves
        FENCE();

        const char* bb = XsB + (q % 3) * 16384 + bko;
        #pragma unroll
        for (int ksl = 0; ksl < 2; ++ksl) {
            #pragma unroll
            for (int wt = 0; wt < 4; ++wt) {
                const char* p0 = bb + ksl * 8192 + slotb[wt];
                float f0  = *(const float*)(p0 + 0 * 256);
                float f1  = *(const float*)(p0 + 1 * 256);
                float f2  = *(const float*)(p0 + 2 * 256);
                float f3  = *(const float*)(p0 + 3 * 256);
                float f4_ = *(const float*)(p0 + 4 * 256);
                float f5  = *(const float*)(p0 + 5 * 256);
                float f6  = *(const float*)(p0 + 6 * 256);
                float f7  = *(const float*)(p0 + 7 * 256);
                union { frag8 fr; unsigned u[4]; } B;
                B.u[0] = cvtpk(f0, f1);
                B.u[1] = cvtpk(f2, f3);
                B.u[2] = cvtpk(f4_, f5);
                B.u[3] = cvtpk(f6, f7);
                #pragma unroll
                for (int ot = 0; ot < 4; ++ot)
                    acc[ot][wt] = __builtin_amdgcn_mfma_f32_16x16x32_bf16(
                        A[ot][ksl], B.fr, acc[ot][wt], 0, 0, 0);
            }
        }
        __builtin_amdgcn_sched_barrier(0);   // compute(q) done before A reuse

        if (q + 1 < 12) {                    // A(q+1): issued AFTER st(q+1),
            #pragma unroll                   // BEFORE st(q+2)  (FIFO position)
            for (int ot = 0; ot < 4; ++ot)
                #pragma unroll
                for (int ksl = 0; ksl < 2; ++ksl)
                    A[ot][ksl] = Afw[(q + 1) * 2048 + wv * 512 + ot * 128 + ksl * 64];
        }
        __builtin_amdgcn_sched_barrier(0);   // pin A(q+1) above STAGE(q+2)
        if (q + 2 < 12) STAGE(q + 2);
    }

    // ---- store: out col = n+1 for n=0..55; cols 0 and 57 are exact zeros
    #pragma unroll
    for (int ot = 0; ot < 4; ++ot) {
        #pragma unroll
        for (int r = 0; r < 4; ++r) {
            int o = wv * 64 + ot * 16 + hi * 4 + r;
            float* orow = out + ((size_t)(b * 256 + o) * HOUT + h) * WOUT;
            #pragma unroll
            for (int wt = 0; wt < 4; ++wt) {
                int n = wt * 16 + lo;
                if (n < 56) orow[n + 1] = acc[ot][wt][r];
            }
            if (lo == 0) orow[0]  = 0.f;
            if (lo == 1) orow[57] = 0.f;
        }
    }
}

extern "C" void kernel_launch(void* const* d_in, const int* in_sizes, int n_in,
                              void* d_out, int out_size, void* d_ws, size_t ws_size,
                              hipStream_t stream) {
    const float* x     = (const float*)d_in[0];   // (32,256,56,56)
    const float* lego  = (const float*)d_in[1];   // (64,64,3,1)
    const float* coefs = (const float*)d_in[2];   // (4,256,64,1,1)
    const float* comb  = (const float*)d_in[3];   // (4,256,64,1,1)
    float* out = (float*)d_out;                   // (32,256,19,58)

    unsigned short* Asw = (unsigned short*)d_ws;  // 196,608 bf16 = 384 KB

    prep_weff<<<dim3(3, 256), 256, 0, stream>>>(lego, coefs, comb, Asw);
    conv_mfma<<<dim3(HOUT, 32), 256, 0, stream>>>(x, Asw, out);
}